// Round 1
// baseline (420.424 us; speedup 1.0000x reference)
//
#include <hip/hip_runtime.h>
#include <hip/hip_bf16.h>

// Problem constants
#define BB    16384   // batch
#define PP    32      // obs dim
#define MCC   16      // control dim
#define HH    24
#define MM    64
#define LL    129           // history length
#define YROW  (LL*PP)       // 4128 floats per batch row
#define KK    (128*PP)      // 4096 contraction length (delays 0..127)

// Main-kernel tiling
#define ROWS   64           // batch rows per block (== lanes)
#define TPB    512          // 8 waves
#define STAGES 16
#define SK     256          // k per stage
#define SROWSTRIDE 265      // swizzled LDS row stride: addr = row*265 + (k>>5)*33 + (k&31)

__device__ __forceinline__ float rl(float v, int lane) {
    return __int_as_float(__builtin_amdgcn_readlane(__float_as_int(v), lane));
}

// ---------------------------------------------------------------------------
// Setup: build Wk[k][c], k = d*32+p, combining all four terms.
// grid 256 blocks (128 d  x 2 c-halves), 256 threads.
// ---------------------------------------------------------------------------
__global__ __launch_bounds__(256) void setup_k(
    const float* __restrict__ M0,  const float* __restrict__ Mt,
    const float* __restrict__ M0l, const float* __restrict__ Mb,
    const float* __restrict__ sig, const float* __restrict__ lam,
    const float* __restrict__ phi, const float* __restrict__ phit,
    float* __restrict__ Wk)
{
    __shared__ float sA[MM*HH];   // phi_tilde[j][i] * lambda[i]^0.25
    __shared__ float sB[MM*HH];   // phi[k][l]      * sigma[l]^0.25
    __shared__ float sWd[HH*HH];  // (lam*sig)^0.25 * conv at n=d-1

    const int t = threadIdx.x;
    const int d = blockIdx.x >> 1;
    const int h = blockIdx.x & 1;

#pragma unroll
    for (int r = 0; r < 6; ++r) {
        int e = t + r*256;            // 6*256 = 1536 = 64*24 exactly
        int col = e % HH;
        sA[e] = phit[e] * sqrtf(sqrtf(lam[col]));
        sB[e] = phi[e]  * sqrtf(sqrtf(sig[col]));
    }
    __syncthreads();

    if (d >= 1) {
        const int n  = d - 1;
        const int lo = n > 63 ? n - 63 : 0;
        const int hi = n < 63 ? n : 63;
        for (int e = t; e < HH*HH; e += 256) {
            int i = e / HH, l = e % HH;
            float s = 0.f;
            for (int j = lo; j <= hi; ++j) s += sA[j*HH + i] * sB[(n - j)*HH + l];
            sWd[e] = s;
        }
    }
    __syncthreads();

    const int c = h*8 + (t >> 5);
    const int p = t & 31;
    float wv = 0.f;
    if (d == 0) wv += M0[c*PP + p];
    if (d >= 1 && d <= MM) {
        const int j = d - 1;
#pragma unroll
        for (int i = 0; i < HH; ++i) wv += sA[j*HH + i] * Mt[(i*MCC + c)*PP + p];
    }
    if (d < MM) {
#pragma unroll
        for (int l = 0; l < HH; ++l) wv += sB[d*HH + l] * M0l[(l*MCC + c)*PP + p];
    }
    if (d >= 1) {
        const float* mb = Mb + h*256 + t;   // (c*32+p) == h*256 + t for t<256
#pragma unroll 16
        for (int e = 0; e < HH*HH; ++e) wv += sWd[e] * mb[e*512];
    }
    Wk[(d*PP + p)*MCC + c] = wv;
}

// ---------------------------------------------------------------------------
// Main: u[b,c] = sum_k Wk[k][c] * y[b][k], 256 blocks x 512 threads.
// lanes = rows; W broadcast from per-lane VGPRs via v_readlane (constant lane).
// ---------------------------------------------------------------------------
__global__ __launch_bounds__(512) void main_k(
    const float* __restrict__ Y, const float* __restrict__ Wk,
    float* __restrict__ out)
{
    __shared__ float sY[ROWS * SROWSTRIDE];   // 67840 B; reused for reduction

    const int t    = threadIdx.x;
    const int w    = t >> 6;          // wave 0..7
    const int lane = t & 63;
    const int blk  = blockIdx.x;

    // staging: thread -> (srow = t>>3, kq = t&7), 32 consecutive k each
    const int srow = t >> 3, kq = t & 7;
    const float* yst = Y + (size_t)(blk*ROWS + srow)*YROW + kq*32;
    const int wbase = srow*SROWSTRIDE + kq*33;

    // compute: lane = row, wave w owns k_loc in [32w, 32w+32) each stage
    const int rbase = lane*SROWSTRIDE + w*33;

    // W fragment: lane holds Wk[(s*256 + w*32 + (lane&31))*16 + (lane>>5)*8 .. +8)
    const float* wst = Wk + ((w*32 + (lane & 31))*MCC + ((lane >> 5) & 1)*8);

    float acc[16];
#pragma unroll
    for (int c = 0; c < 16; ++c) acc[c] = 0.f;

    float4 Yr[8], Wn0, Wn1, Wc0, Wc1;
    // prologue: stage 0 into registers
#pragma unroll
    for (int i = 0; i < 8; ++i) Yr[i] = *(const float4*)(yst + 4*i);
    Wn0 = *(const float4*)(wst + 0);
    Wn1 = *(const float4*)(wst + 4);

#pragma unroll 1
    for (int s = 0; s < STAGES; ++s) {
        __syncthreads();
#pragma unroll
        for (int i = 0; i < 8; ++i) {
            int a = wbase + 4*i;
            sY[a + 0] = Yr[i].x; sY[a + 1] = Yr[i].y;
            sY[a + 2] = Yr[i].z; sY[a + 3] = Yr[i].w;
        }
        __syncthreads();

        Wc0 = Wn0; Wc1 = Wn1;
        if (s < STAGES - 1) {
            const float* yp = yst + (s + 1)*SK;
#pragma unroll
            for (int i = 0; i < 8; ++i) Yr[i] = *(const float4*)(yp + 4*i);
            const float* wp = wst + (s + 1)*SK*MCC;
            Wn0 = *(const float4*)(wp + 0);
            Wn1 = *(const float4*)(wp + 4);
        }

#pragma unroll
        for (int j = 0; j < 32; ++j) {
            float yv = sY[rbase + j];
            acc[0]  = fmaf(rl(Wc0.x, j     ), yv, acc[0]);
            acc[1]  = fmaf(rl(Wc0.y, j     ), yv, acc[1]);
            acc[2]  = fmaf(rl(Wc0.z, j     ), yv, acc[2]);
            acc[3]  = fmaf(rl(Wc0.w, j     ), yv, acc[3]);
            acc[4]  = fmaf(rl(Wc1.x, j     ), yv, acc[4]);
            acc[5]  = fmaf(rl(Wc1.y, j     ), yv, acc[5]);
            acc[6]  = fmaf(rl(Wc1.z, j     ), yv, acc[6]);
            acc[7]  = fmaf(rl(Wc1.w, j     ), yv, acc[7]);
            acc[8]  = fmaf(rl(Wc0.x, j + 32), yv, acc[8]);
            acc[9]  = fmaf(rl(Wc0.y, j + 32), yv, acc[9]);
            acc[10] = fmaf(rl(Wc0.z, j + 32), yv, acc[10]);
            acc[11] = fmaf(rl(Wc0.w, j + 32), yv, acc[11]);
            acc[12] = fmaf(rl(Wc1.x, j + 32), yv, acc[12]);
            acc[13] = fmaf(rl(Wc1.y, j + 32), yv, acc[13]);
            acc[14] = fmaf(rl(Wc1.z, j + 32), yv, acc[14]);
            acc[15] = fmaf(rl(Wc1.w, j + 32), yv, acc[15]);
        }
    }

    // cross-wave reduction: 8 partials per (row, c)
    __syncthreads();
    float* red = sY;                       // [t][16] = [(w*64+lane)][16], 32 KB
#pragma unroll
    for (int c = 0; c < 16; ++c) red[t*16 + c] = acc[c];
    __syncthreads();

    if (t < 256) {
        const int row = t >> 2, c4 = t & 3;
        float4 sum = make_float4(0.f, 0.f, 0.f, 0.f);
#pragma unroll
        for (int ww = 0; ww < 8; ++ww) {
            const float* rp = &red[(ww*64 + row)*16 + c4*4];
            sum.x += rp[0]; sum.y += rp[1]; sum.z += rp[2]; sum.w += rp[3];
        }
        *(float4*)(out + (size_t)(blk*ROWS + row)*MCC + c4*4) = sum;
    }
}

extern "C" void kernel_launch(void* const* d_in, const int* in_sizes, int n_in,
                              void* d_out, int out_size, void* d_ws, size_t ws_size,
                              hipStream_t stream) {
    (void)in_sizes; (void)n_in; (void)out_size; (void)ws_size;
    const float* y    = (const float*)d_in[0];
    const float* M0   = (const float*)d_in[1];
    const float* Mt   = (const float*)d_in[2];
    const float* M0l  = (const float*)d_in[3];
    const float* Mb   = (const float*)d_in[4];
    const float* sig  = (const float*)d_in[5];
    const float* lam  = (const float*)d_in[6];
    const float* phi  = (const float*)d_in[7];
    const float* phit = (const float*)d_in[8];

    float* Wk  = (float*)d_ws;          // 4096*16*4 = 256 KB scratch
    float* out = (float*)d_out;

    setup_k<<<256, 256, 0, stream>>>(M0, Mt, M0l, Mb, sig, lam, phi, phit, Wk);
    main_k<<<256, TPB, 0, stream>>>(y, Wk, out);
}